// Round 12
// baseline (74.189 us; speedup 1.0000x reference)
//
#include <hip/hip_runtime.h>
#include <math.h>

#define NG 512
#define HH 256
#define WW 256
#define TILE 8
#define TXN (WW / TILE)      // 32 tiles across
#define TYN (HH / TILE)      // 32 tiles down
#define NTILES (TXN * TYN)   // 1024
#define CHUNKS 8
#define NACC 13
#define S_CUT 12.0f          // skip when sigma > 12: alpha < opac*e^-12 ~ 3e-6

__device__ __forceinline__ float softplus_f(float x) {
    if (x > 20.0f) return x;
    if (x < -20.0f) return expf(x);
    return log1pf(expf(x));
}

__device__ __forceinline__ float sigmoid_f(float x) {
    return 1.0f / (1.0f + expf(-x));
}

// Single fused kernel. One block per 8x8 tile; 512 threads = 8 waves.
// Phase 1 (fused prep): thread t computes gaussian t's params into LDS and
// tests its S_CUT ellipse AABB against this tile; wave-wide ballot builds the
// survivor mask for chunk wv = t>>6 (lane g <-> gaussian wv*64+g).
// Phase 2: ctz iteration over survivors, exact front-to-back order, running T.
// Phase 3: chunked-transmittance merge in LDS (accumulators linear in entry-T).
// LDS reuse: params buffer is aliased by the accumulator buffer; the
// __syncthreads() after the Tl write separates ALL param reads (phase 2)
// from ALL acc writes (phase 3), so the alias is race-free.
__global__ __launch_bounds__(512, 8)
void render_kernel(const float* __restrict__ means,
                   const float* __restrict__ chol,
                   const float* __restrict__ rgbl,
                   const float* __restrict__ opl,
                   float* __restrict__ out) {
    const int tid  = threadIdx.x;
    const int lane = tid & 63;
    const int wv   = tid >> 6;                 // chunk id 0..7
    const int tx   = blockIdx.x & (TXN - 1);
    const int ty   = blockIdx.x >> 5;
    const int x0   = tx * TILE;
    const int y0   = ty * TILE;
    const float px = (float)(x0 + (lane & 7)) + 0.5f;
    const float py = (float)(y0 + (lane >> 3)) + 0.5f;

    __shared__ float shbuf[NACC * CHUNKS * 64];   // 26.6 KB: params then accL
    __shared__ float Tl[CHUNKS][64];              // 2 KB

    // ---- fused prep: gaussian tid -> LDS params + tile-overlap ballot ----
    bool hit;
    {
        float L11 = softplus_f(chol[3*tid + 0]);
        float L21 = chol[3*tid + 1];
        float L22 = softplus_f(chol[3*tid + 2]);
        float s00 = L11 * L11;                 // Sigma_xx
        float s01 = L11 * L21;
        float s11 = L21 * L21 + L22 * L22;     // Sigma_yy
        float dd  = L11 * L22;
        float inv = 1.0f / (dd * dd);
        float mx  = means[2*tid + 0];
        float my  = means[2*tid + 1];
        float4* p4 = (float4*)shbuf;
        p4[3*tid + 0] = make_float4(mx, my, s11 * inv, -s01 * inv);
        p4[3*tid + 1] = make_float4(s00 * inv, sigmoid_f(opl[tid]),
                                    sigmoid_f(rgbl[3*tid + 0]),
                                    sigmoid_f(rgbl[3*tid + 1]));
        p4[3*tid + 2] = make_float4(sigmoid_f(rgbl[3*tid + 2]), 0.f, 0.f, 0.f);
        // conservative AABB of {sigma <= S_CUT}: |dX| <= sqrt(2*S_CUT*Sigma_xx)
        float ex = sqrtf(2.0f * S_CUT * s00);
        float ey = sqrtf(2.0f * S_CUT * s11);
        hit = (mx - ex < (float)(x0 + TILE)) && (mx + ex > (float)x0) &&
              (my - ey < (float)(y0 + TILE)) && (my + ey > (float)y0);
    }
    unsigned long long m = __ballot(hit ? 1 : 0);  // survivor mask for chunk wv
    __syncthreads();                                // params visible to all waves

    const float4* __restrict__ g4 = (const float4*)shbuf;
    const int cbase = wv * 64;

    float T = 1.0f;
    float ir = 0.f, ig = 0.f, ib = 0.f, wsum = 0.f;
    float xr = 0.f, xg = 0.f, xb = 0.f;
    float yr = 0.f, yg = 0.f, yb = 0.f;
    float qr = 0.f, qg = 0.f, qb = 0.f;

    while (m) {
        int n = __builtin_ctzll(m);
        m &= (m - 1);
        int gi = __builtin_amdgcn_readfirstlane(cbase + n);  // wave-uniform
        float4 P0 = g4[3*gi + 0];   // mx, my, a, b   (LDS broadcast reads)
        float4 P1 = g4[3*gi + 1];   // c, opac, r, g
        float4 P2 = g4[3*gi + 2];   // bcol, -, -, -
        float dX = P0.x - px;
        float dY = P0.y - py;
        float a = P0.z, b = P0.w, c = P1.x, opac = P1.y;
        float gx = a * dX + b * dY;
        float gy = b * dX + c * dY;
        float s  = 0.5f * (dX * gx + dY * gy);
        float e  = __expf(-s);
        float alpha = fminf(opac * e, 0.999f);
        float vis = alpha * T;
        T = T - alpha * T;
        wsum += vis;
        float r = P1.z, g = P1.w, bcol = P2.x;
        ir += vis * r;  ig += vis * g;  ib += vis * bcol;
        float vgx = vis * gx;
        float vgy = vis * gy;
        xr += vgx * r;  xg += vgx * g;  xb += vgx * bcol;
        yr += vgy * r;  yg += vgy * g;  yb += vgy * bcol;
        float q  = gx * gy - b;
        float vq = vis * q;
        qr += vq * r;   qg += vq * g;   qb += vq * bcol;
    }

    // --- merge chunks across waves; shbuf now reused as accL[NACC][CHUNKS][64] ---
    Tl[wv][lane] = T;
    __syncthreads();   // ALL param reads done before shbuf is overwritten below

    float scale = 1.0f;
    for (int i = 0; i < wv; ++i) scale *= Tl[i][lane];  // wave-uniform trip count

    float* accF = shbuf;
    #define ACC(comp) accF[(comp) * (CHUNKS * 64) + wv * 64 + lane]
    ACC(0)  = ir   * scale;
    ACC(1)  = ig   * scale;
    ACC(2)  = ib   * scale;
    ACC(3)  = wsum * scale;
    ACC(4)  = xr   * scale;
    ACC(5)  = xg   * scale;
    ACC(6)  = xb   * scale;
    ACC(7)  = yr   * scale;
    ACC(8)  = yg   * scale;
    ACC(9)  = yb   * scale;
    ACC(10) = qr   * scale;
    ACC(11) = qg   * scale;
    ACC(12) = qb   * scale;
    #undef ACC
    __syncthreads();

    const int HW = HH * WW;
    for (int v = tid; v < 64 * NACC; v += 512) {
        int pp   = v / NACC;
        int comp = v - pp * NACC;
        float s = 0.f;
        #pragma unroll
        for (int cch = 0; cch < CHUNKS; ++cch)
            s += accF[comp * (CHUNKS * 64) + cch * 64 + pp];
        int p = (y0 + (pp >> 3)) * WW + x0 + (pp & 7);
        if (comp < 3) {
            out[comp * HW + p] = s;                 // render [c][h][w]
            out[3 * HW + 3 * p + comp] = s;         // img [h][w][c]
        } else if (comp == 3) {
            out[6 * HW + p] = s;                    // wsum
        } else if (comp < 7) {
            out[7 * HW + 3 * p + (comp - 4)] = s;   // dx_img
        } else if (comp < 10) {
            out[10 * HW + 3 * p + (comp - 7)] = s;  // dy_img
        } else {
            out[13 * HW + 3 * p + (comp - 10)] = s; // dxy_img
        }
    }
}

extern "C" void kernel_launch(void* const* d_in, const int* in_sizes, int n_in,
                              void* d_out, int out_size, void* d_ws, size_t ws_size,
                              hipStream_t stream) {
    const float* means = (const float*)d_in[0];
    const float* chol  = (const float*)d_in[1];
    const float* rgbl  = (const float*)d_in[2];
    const float* opl   = (const float*)d_in[3];
    float* out = (float*)d_out;

    render_kernel<<<dim3(NTILES), dim3(512), 0, stream>>>(means, chol, rgbl, opl, out);
}

// Round 14
// 72.331 us; speedup vs baseline: 1.0257x; 1.0257x over previous
//
#include <hip/hip_runtime.h>
#include <math.h>

#define NG 512
#define HH 256
#define WW 256
#define TILE 8
#define TXN (WW / TILE)      // 32 tiles across
#define TYN (HH / TILE)      // 32 tiles down
#define NTILES (TXN * TYN)   // 1024
#define CHUNKS 8
#define NACC 13
#define S_CUT 12.0f          // skip when sigma > 12: alpha < opac*e^-12 ~ 3e-6

__device__ __forceinline__ float softplus_f(float x) {
    if (x > 20.0f) return x;
    if (x < -20.0f) return expf(x);
    return log1pf(expf(x));
}

__device__ __forceinline__ float sigmoid_f(float x) {
    return 1.0f / (1.0f + expf(-x));
}

// Per-gaussian params: [mx, my, a, b] [c, opac, r, g] [bcol, 0,0,0] — 3 float4.
// Plus conservative tile-index AABB of the {sigma <= S_CUT} ellipse:
// max |dX| on the level set = sqrt(2*S_CUT*Sigma_xx), Sigma_xx = L11^2.
__global__ void prep_kernel(const float* __restrict__ means,
                            const float* __restrict__ chol,
                            const float* __restrict__ rgbl,
                            const float* __restrict__ opl,
                            float* __restrict__ params,
                            int4* __restrict__ tb) {
    int n = blockIdx.x * blockDim.x + threadIdx.x;
    if (n >= NG) return;
    float L11 = softplus_f(chol[3*n + 0]);
    float L21 = chol[3*n + 1];
    float L22 = softplus_f(chol[3*n + 2]);
    float s00 = L11 * L11;                 // Sigma_xx
    float s01 = L11 * L21;
    float s11 = L21 * L21 + L22 * L22;     // Sigma_yy
    float d  = L11 * L22;
    float inv = 1.0f / (d * d);
    float mx = means[2*n + 0];
    float my = means[2*n + 1];
    float* p = params + 12 * n;
    p[0] = mx;
    p[1] = my;
    p[2] =  s11 * inv;
    p[3] = -s01 * inv;
    p[4] =  s00 * inv;
    p[5] = sigmoid_f(opl[n]);
    p[6] = sigmoid_f(rgbl[3*n + 0]);
    p[7] = sigmoid_f(rgbl[3*n + 1]);
    p[8] = sigmoid_f(rgbl[3*n + 2]);
    p[9] = 0.0f; p[10] = 0.0f; p[11] = 0.0f;

    float ex = sqrtf(2.0f * S_CUT * s00);
    float ey = sqrtf(2.0f * S_CUT * s11);
    int4 r;
    r.x = max(0,       (int)floorf((mx - ex) * (1.0f / TILE)));   // tx0
    r.y = min(TXN - 1, (int)floorf((mx + ex) * (1.0f / TILE)));   // tx1
    r.z = max(0,       (int)floorf((my - ey) * (1.0f / TILE)));   // ty0
    r.w = min(TYN - 1, (int)floorf((my + ey) * (1.0f / TILE)));   // ty1
    tb[n] = r;
}

// One block per 8x8 tile; 512 threads = 8 waves; wave w owns gaussian chunk
// [64w, 64w+64). Lane g ballots its gaussian's tile-AABB vs this tile -> 64-bit
// survivor mask; ctz iteration preserves front-to-back order exactly.
// Chunked transmittance merge as before (accumulators linear in entry-T).
__global__ __launch_bounds__(512, 8)
void render_kernel(const float* __restrict__ params,
                   const int4* __restrict__ tb,
                   float* __restrict__ out) {
    const int lane = threadIdx.x & 63;
    const int wv   = threadIdx.x >> 6;         // chunk id 0..7
    const int tx   = blockIdx.x & (TXN - 1);
    const int ty   = blockIdx.x >> 5;
    const int x0   = tx * TILE;
    const int y0   = ty * TILE;
    const float px = (float)(x0 + (lane & 7)) + 0.5f;
    const float py = (float)(y0 + (lane >> 3)) + 0.5f;

    // build this wave's survivor mask: lane g tests gaussian wv*64+g
    int4 bb = tb[threadIdx.x];
    bool hit = (tx >= bb.x) && (tx <= bb.y) && (ty >= bb.z) && (ty <= bb.w);
    unsigned long long m = __ballot(hit ? 1 : 0);

    const float4* __restrict__ g4 = (const float4*)params;
    const int cbase = wv * 64;

    float T = 1.0f;
    float ir = 0.f, ig = 0.f, ib = 0.f, wsum = 0.f;
    float xr = 0.f, xg = 0.f, xb = 0.f;
    float yr = 0.f, yg = 0.f, yb = 0.f;
    float qr = 0.f, qg = 0.f, qb = 0.f;

    while (m) {
        int n = __builtin_ctzll(m);
        m &= (m - 1);
        int gi = __builtin_amdgcn_readfirstlane(cbase + n);  // wave-uniform index
        float4 P0 = g4[3*gi + 0];   // mx, my, a, b
        float4 P1 = g4[3*gi + 1];   // c, opac, r, g
        float4 P2 = g4[3*gi + 2];   // bcol, -, -, -
        float dX = P0.x - px;
        float dY = P0.y - py;
        float a = P0.z, b = P0.w, c = P1.x, opac = P1.y;
        float gx = a * dX + b * dY;
        float gy = b * dX + c * dY;
        float s  = 0.5f * (dX * gx + dY * gy);
        float e  = __expf(-s);
        float alpha = fminf(opac * e, 0.999f);
        float vis = alpha * T;
        T = T - alpha * T;
        wsum += vis;
        float r = P1.z, g = P1.w, bcol = P2.x;
        ir += vis * r;  ig += vis * g;  ib += vis * bcol;
        float vgx = vis * gx;
        float vgy = vis * gy;
        xr += vgx * r;  xg += vgx * g;  xb += vgx * bcol;
        yr += vgy * r;  yg += vgy * g;  yb += vgy * bcol;
        float q  = gx * gy - b;
        float vq = vis * q;
        qr += vq * r;   qg += vq * g;   qb += vq * bcol;
    }

    // --- merge chunks across waves via LDS (28.6 KB/block) ---
    __shared__ float Tl[CHUNKS][64];
    __shared__ float accL[NACC][CHUNKS][64];
    Tl[wv][lane] = T;
    __syncthreads();

    float scale = 1.0f;
    for (int i = 0; i < wv; ++i) scale *= Tl[i][lane];  // wave-uniform trip count

    accL[ 0][wv][lane] = ir   * scale;
    accL[ 1][wv][lane] = ig   * scale;
    accL[ 2][wv][lane] = ib   * scale;
    accL[ 3][wv][lane] = wsum * scale;
    accL[ 4][wv][lane] = xr   * scale;
    accL[ 5][wv][lane] = xg   * scale;
    accL[ 6][wv][lane] = xb   * scale;
    accL[ 7][wv][lane] = yr   * scale;
    accL[ 8][wv][lane] = yg   * scale;
    accL[ 9][wv][lane] = yb   * scale;
    accL[10][wv][lane] = qr   * scale;
    accL[11][wv][lane] = qg   * scale;
    accL[12][wv][lane] = qb   * scale;
    __syncthreads();

    const int HW = HH * WW;
    for (int v = threadIdx.x; v < 64 * NACC; v += 512) {
        int pp   = v / NACC;
        int comp = v - pp * NACC;
        float s = 0.f;
        #pragma unroll
        for (int cch = 0; cch < CHUNKS; ++cch) s += accL[comp][cch][pp];
        int p = (y0 + (pp >> 3)) * WW + x0 + (pp & 7);
        if (comp < 3) {
            out[comp * HW + p] = s;                 // render [c][h][w]
            out[3 * HW + 3 * p + comp] = s;         // img [h][w][c]
        } else if (comp == 3) {
            out[6 * HW + p] = s;                    // wsum
        } else if (comp < 7) {
            out[7 * HW + 3 * p + (comp - 4)] = s;   // dx_img
        } else if (comp < 10) {
            out[10 * HW + 3 * p + (comp - 7)] = s;  // dy_img
        } else {
            out[13 * HW + 3 * p + (comp - 10)] = s; // dxy_img
        }
    }
}

extern "C" void kernel_launch(void* const* d_in, const int* in_sizes, int n_in,
                              void* d_out, int out_size, void* d_ws, size_t ws_size,
                              hipStream_t stream) {
    const float* means = (const float*)d_in[0];
    const float* chol  = (const float*)d_in[1];
    const float* rgbl  = (const float*)d_in[2];
    const float* opl   = (const float*)d_in[3];
    float* out = (float*)d_out;
    float* params = (float*)d_ws;                       // 512*12 floats = 24 KB
    int4*  tb     = (int4*)((char*)d_ws + 24 * 1024);   // 512*16 B = 8 KB

    prep_kernel<<<dim3(2), dim3(256), 0, stream>>>(means, chol, rgbl, opl, params, tb);
    render_kernel<<<dim3(NTILES), dim3(512), 0, stream>>>(params, tb, out);
}